// Round 4
// baseline (28411.566 us; speedup 1.0000x reference)
//
#include <hip/hip_runtime.h>

// ---------------------------------------------------------------------------
// FocusModel: embed -> bidir LSTM (E=512->HE=512) -> bidir LSTM (1024->512)
//          -> decoder LSTM (HD=1024, one-hot argmax feedback) -> softmax/loss
// R7: R6 passed but the decoder ran 79 us/step with all pipes idle: the
// single-line barrier serialized 128 remote fetch_adds (~25 us/barrier), and
// phase-B LDS staging had 32-way bank conflicts. This round:
//   - 32 blocks x 256 threads (4 waves) everywhere persistent: barrier
//     participants 128 -> 32; 4 waves/CU hide LLC latency.
//   - distributed generation-free barrier: per-barrier-instance set of 8
//     cache-line counters (pre-zeroed); arrival = RELEASE fetch_add on line
//     (bi&7); wait = lanes 0-7 poll 8 lines, shuffle-sum == 32. No acquire,
//     no reset, no buffer_inv. Cross-XCD visibility: RELEASE writeback at
//     arrival + ring-fresh addresses / agent-scope atomic loads (as R6).
//   - phase-B staging via u32 lane-stride-1 atomic loads (conflict-free LDS).
// Math identical to the verified R3/R5/R6 kernels.
// ---------------------------------------------------------------------------

typedef __bf16 bf16_t;
typedef __bf16 bf16x8 __attribute__((ext_vector_type(8)));
typedef __bf16 bf16x4 __attribute__((ext_vector_type(4)));
typedef float  f32x4  __attribute__((ext_vector_type(4)));

#define NB 128
#define LQ 160
#define EE 512
#define HE 512
#define HD 1024
#define TT 128

__device__ __forceinline__ f32x4 mfma16(bf16x8 a, bf16x8 b, f32x4 c) {
    return __builtin_amdgcn_mfma_f32_16x16x32_bf16(a, b, c, 0, 0, 0);
}
__device__ __forceinline__ bf16x8 ldf(const bf16_t* p) { return *(const bf16x8*)p; }
__device__ __forceinline__ float sigf(float x) { return 1.0f / (1.0f + __expf(-x)); }

// 8 f32 -> bf16x8 (RNE, same numerics as k_cvt).
__device__ __forceinline__ bf16x8 cvt8(const float* p) {
    float4 f0 = ((const float4*)p)[0];
    float4 f1 = ((const float4*)p)[1];
    bf16x8 a;
    a[0] = (bf16_t)f0.x; a[1] = (bf16_t)f0.y; a[2] = (bf16_t)f0.z; a[3] = (bf16_t)f0.w;
    a[4] = (bf16_t)f1.x; a[5] = (bf16_t)f1.y; a[6] = (bf16_t)f1.z; a[7] = (bf16_t)f1.w;
    return a;
}

// ---------------------------------------------------------------------------
// Distributed grid barrier, generation-free. Each barrier instance owns 8
// cache lines (8 x 16 u32 = 512 B), pre-zeroed once on the host. Arrival:
// RELEASE fetch_add on line (blockIdx&7) -> drains vmcnt + writes back dirty
// L2 (producers' stores reach the coherent point); <=4 serialized RMWs/line.
// Wait: lanes 0-7 poll the 8 lines (relaxed agent loads), butterfly-sum.
// ---------------------------------------------------------------------------
#define BAR_STRIDE 128  // u32s per barrier instance (8 lines x 16 u32)
__device__ __forceinline__ void gbar(unsigned* __restrict__ bars, int& bidx,
                                     unsigned nblk) {
    unsigned* lines = bars + (size_t)bidx * BAR_STRIDE;
    __syncthreads();  // all waves' stores drained (compiler emits vmcnt(0))
    if (threadIdx.x == 0)
        __hip_atomic_fetch_add(lines + (blockIdx.x & 7) * 16, 1u,
                               __ATOMIC_RELEASE, __HIP_MEMORY_SCOPE_AGENT);
    if (threadIdx.x < 8) {
        for (;;) {
            unsigned s = __hip_atomic_load(lines + threadIdx.x * 16,
                                           __ATOMIC_RELAXED,
                                           __HIP_MEMORY_SCOPE_AGENT);
            s += __shfl_xor(s, 1);
            s += __shfl_xor(s, 2);
            s += __shfl_xor(s, 4);
            if (s >= nblk) break;
            __builtin_amdgcn_s_sleep(1);
        }
    }
    __syncthreads();
    ++bidx;
}

// f32 -> bf16 bulk convert (n4 = n/4, all sizes divisible by 4).
__global__ __launch_bounds__(256) void k_cvt(const float* __restrict__ src,
                                             bf16_t* __restrict__ dst, int n4) {
    int i = blockIdx.x * 256 + threadIdx.x;
    if (i < n4) {
        float4 v = ((const float4*)src)[i];
        bf16x4 o;
        o[0] = (bf16_t)v.x; o[1] = (bf16_t)v.y; o[2] = (bf16_t)v.z; o[3] = (bf16_t)v.w;
        ((bf16x4*)dst)[i] = o;
    }
}

// ---------------------------------------------------------------------------
// Chunked input projection, layer 0. Rows m = (s-s0)*128 + b; per-direction
// source timestep t = d ? L-1-s : s; A-row = embed[ids[b][t]] (f32 gather,
// converted in-register). grid (CH*2, 32, 2), block 64.
// ---------------------------------------------------------------------------
__global__ __launch_bounds__(64) void k_xg0c(const int* __restrict__ ids,
                                             const float* __restrict__ embed,
                                             const bf16_t* __restrict__ wih,
                                             bf16_t* __restrict__ xgc,
                                             int s0) {
    const int lane = threadIdx.x;
    const int l15 = lane & 15, quad = lane >> 4;
    const int m0 = blockIdx.x * 64;
    const int n0 = blockIdx.y * 64;
    const int d  = blockIdx.z;
    const bf16_t* Wd = wih + (size_t)d * 2048 * 512;

    const float* arow[4];
#pragma unroll
    for (int mi = 0; mi < 4; ++mi) {
        int m = m0 + mi * 16 + l15;
        int b = m & 127, s = s0 + (m >> 7);
        int t = d ? (LQ - 1 - s) : s;
        int id = ids[b * LQ + t];
        arow[mi] = embed + (size_t)id * EE;
    }
    const bf16_t* brow[4];
#pragma unroll
    for (int ni = 0; ni < 4; ++ni) brow[ni] = Wd + (size_t)(n0 + ni * 16 + l15) * 512;

    f32x4 acc[4][4] = {};
    for (int kb = 0; kb < 512; kb += 32) {
        bf16x8 af[4], bfr[4];
#pragma unroll
        for (int mi = 0; mi < 4; ++mi) af[mi] = cvt8(arow[mi] + kb + quad * 8);
#pragma unroll
        for (int ni = 0; ni < 4; ++ni) bfr[ni] = ldf(brow[ni] + kb + quad * 8);
#pragma unroll
        for (int mi = 0; mi < 4; ++mi)
#pragma unroll
            for (int ni = 0; ni < 4; ++ni)
                acc[mi][ni] = mfma16(af[mi], bfr[ni], acc[mi][ni]);
    }
#pragma unroll
    for (int mi = 0; mi < 4; ++mi)
#pragma unroll
        for (int ni = 0; ni < 4; ++ni)
#pragma unroll
            for (int r = 0; r < 4; ++r) {
                int m = m0 + mi * 16 + quad * 4 + r;
                int n = n0 + ni * 16 + l15;
                xgc[(size_t)m * 4096 + d * 2048 + n] = (bf16_t)acc[mi][ni][r];
            }
}

// Chunked input projection, layer 1: A-row = h1ring[1+t][b] (1024 wide), K=1024.
__global__ __launch_bounds__(64) void k_xg1c(const bf16_t* __restrict__ h1,
                                             const bf16_t* __restrict__ wih,
                                             bf16_t* __restrict__ xgc,
                                             int s0) {
    const int lane = threadIdx.x;
    const int l15 = lane & 15, quad = lane >> 4;
    const int m0 = blockIdx.x * 64;
    const int n0 = blockIdx.y * 64;
    const int d  = blockIdx.z;
    const bf16_t* Wd = wih + (size_t)d * 2048 * 1024;

    const bf16_t* arow[4];
#pragma unroll
    for (int mi = 0; mi < 4; ++mi) {
        int m = m0 + mi * 16 + l15;
        int b = m & 127, s = s0 + (m >> 7);
        int t = d ? (LQ - 1 - s) : s;
        arow[mi] = h1 + ((size_t)(1 + t) * NB + b) * 1024;
    }
    const bf16_t* brow[4];
#pragma unroll
    for (int ni = 0; ni < 4; ++ni) brow[ni] = Wd + (size_t)(n0 + ni * 16 + l15) * 1024;

    f32x4 acc[4][4] = {};
    for (int kb = 0; kb < 1024; kb += 32) {
        bf16x8 af[4], bfr[4];
#pragma unroll
        for (int mi = 0; mi < 4; ++mi) af[mi] = ldf(arow[mi] + kb + quad * 8);
#pragma unroll
        for (int ni = 0; ni < 4; ++ni) bfr[ni] = ldf(brow[ni] + kb + quad * 8);
#pragma unroll
        for (int mi = 0; mi < 4; ++mi)
#pragma unroll
            for (int ni = 0; ni < 4; ++ni)
                acc[mi][ni] = mfma16(af[mi], bfr[ni], acc[mi][ni]);
    }
#pragma unroll
    for (int mi = 0; mi < 4; ++mi)
#pragma unroll
        for (int ni = 0; ni < 4; ++ni)
#pragma unroll
            for (int r = 0; r < 4; ++r) {
                int m = m0 + mi * 16 + quad * 4 + r;
                int n = n0 + ni * 16 + l15;
                xgc[(size_t)m * 4096 + d * 2048 + n] = (bf16_t)acc[mi][ni][r];
            }
}

// ---------------------------------------------------------------------------
// Persistent encoder chunk. 32 blocks x 256 thr (4 waves). Wave-tile index
// wt = bi*4 + w: d = wt>>6, m0 = ((wt>>5)&1)*64, c0 = (wt&31)*16; per-wave
// tile 64 batch x (4 gates x 16 cols), K=512 (same math as R6). Recurrent h
// lives in the per-timestep ring hring[1+t][b][d*512+c] (slots 0, LQ+1 = 0).
// Cell state in registers across the chunk; persisted to cst between chunks.
// ---------------------------------------------------------------------------
__global__ __launch_bounds__(256) void k_enc_chunk(bf16_t* __restrict__ hring,
                                                   const bf16_t* __restrict__ whh,
                                                   const float* __restrict__ bias,
                                                   const bf16_t* __restrict__ xgc,
                                                   float* __restrict__ cst,
                                                   unsigned* __restrict__ bars,
                                                   int s0, int nsteps) {
    const int tid = threadIdx.x;
    const int lane = tid & 63, w = tid >> 6;
    const int wt = blockIdx.x * 4 + w;
    const int l15 = lane & 15, quad = lane >> 4;
    const int m0 = ((wt >> 5) & 1) * 64;
    const int c0 = (wt & 31) * 16;
    const int d  = wt >> 6;
    int bidx = 0;

    const bf16_t* Wd = whh + (size_t)d * 2048 * 512;
    const bf16_t* brow[4];
#pragma unroll
    for (int g4 = 0; g4 < 4; ++g4) brow[g4] = Wd + (size_t)(g4 * 512 + c0 + l15) * 512;
    const int c = c0 + l15;
    float bv[4];
#pragma unroll
    for (int g4 = 0; g4 < 4; ++g4) bv[g4] = bias[d * 2048 + g4 * 512 + c];
    size_t aoff[4];
#pragma unroll
    for (int mi = 0; mi < 4; ++mi) aoff[mi] = (size_t)(m0 + mi * 16 + l15) * 1024;

    // cell state in registers (wave ownership constant across steps)
    float creg[4][4];
#pragma unroll
    for (int mi = 0; mi < 4; ++mi)
#pragma unroll
        for (int r = 0; r < 4; ++r) {
            int m = m0 + mi * 16 + quad * 4 + r;
            creg[mi][r] = cst[((size_t)d * NB + m) * 512 + c];
        }

    for (int s = s0; s < s0 + nsteps; ++s) {
        const int t     = d ? (LQ - 1 - s) : s;
        const int tprev = d ? (LQ - s)     : (s - 1);
        const bf16_t* abase = hring + ((size_t)(1 + tprev) * NB) * 1024 + (size_t)d * 512;

        f32x4 acc[4][4] = {};  // [mi][gate]
        for (int kb = 0; kb < 512; kb += 32) {
            bf16x8 af[4], bfr[4];
#pragma unroll
            for (int mi = 0; mi < 4; ++mi) af[mi] = ldf(abase + aoff[mi] + kb + quad * 8);
#pragma unroll
            for (int g4 = 0; g4 < 4; ++g4) bfr[g4] = ldf(brow[g4] + kb + quad * 8);
#pragma unroll
            for (int mi = 0; mi < 4; ++mi)
#pragma unroll
                for (int g4 = 0; g4 < 4; ++g4)
                    acc[mi][g4] = mfma16(af[mi], bfr[g4], acc[mi][g4]);
        }

        bf16_t* wbase = hring + ((size_t)(1 + t) * NB) * 1024 + (size_t)d * 512;
#pragma unroll
        for (int mi = 0; mi < 4; ++mi)
#pragma unroll
            for (int r = 0; r < 4; ++r) {
                int m = m0 + mi * 16 + quad * 4 + r;
                size_t xoff = ((size_t)(s - s0) * NB + m) * 4096 + (size_t)d * 2048;
                float gi = acc[mi][0][r] + (float)xgc[xoff + 0 * 512 + c] + bv[0];
                float gf = acc[mi][1][r] + (float)xgc[xoff + 1 * 512 + c] + bv[1];
                float gg = acc[mi][2][r] + (float)xgc[xoff + 2 * 512 + c] + bv[2];
                float go = acc[mi][3][r] + (float)xgc[xoff + 3 * 512 + c] + bv[3];
                float cn = sigf(gf) * creg[mi][r] + sigf(gi) * tanhf(gg);
                float hn = sigf(go) * tanhf(cn);
                creg[mi][r] = cn;
                wbase[(size_t)m * 1024 + c] = (bf16_t)hn;
            }
        if (s + 1 < s0 + nsteps) gbar(bars, bidx, 32);
    }

#pragma unroll
    for (int mi = 0; mi < 4; ++mi)
#pragma unroll
        for (int r = 0; r < 4; ++r) {
            int m = m0 + mi * 16 + quad * 4 + r;
            cst[((size_t)d * NB + m) * 512 + c] = creg[mi][r];
        }
}

// ---------------------------------------------------------------------------
// Persistent decoder: init + 160 steps, 32 blocks x 256 thr (4 waves).
// Wave-tile ct = bi*4 + w: phase A tile m0 = (ct>>6)*64, c0 = (ct&63)*16
// (gate GEMM K=1024 + cell, cells in regs); phase B: wave handles batch
// b = ct; hdec row staged via u32 agent atomic loads (lane-stride-1, LDS
// conflict-free); shuffle softmax / first-max argmax / in-register loss.
// ---------------------------------------------------------------------------
__global__ __launch_bounds__(256) void k_dec_persist(const bf16_t* __restrict__ encb,
                                                     const bf16_t* __restrict__ whh,
                                                     const float* __restrict__ bias,
                                                     const float* __restrict__ wih,
                                                     const float* __restrict__ out_w,
                                                     const float* __restrict__ out_b,
                                                     const int* __restrict__ tags,
                                                     bf16_t* __restrict__ hseq,
                                                     float* __restrict__ hdec,
                                                     int* __restrict__ idx,
                                                     unsigned* __restrict__ bars,
                                                     float* __restrict__ prob_out,
                                                     float* __restrict__ loss_out) {
    const int tid = threadIdx.x;
    const int lane = tid & 63, w = tid >> 6;
    const int bi = blockIdx.x;
    const int ct = bi * 4 + w;
    const int l15 = lane & 15, quad = lane >> 4;
    const int m0 = (ct >> 6) * 64;
    const int c0 = (ct & 63) * 16;
    const int c = c0 + l15;
    int bidx = 0;
    __shared__ float hrow[4 * HD];

    // ---- init own tile: hseq[0] = enc[0] (ring slot 1), c0 = [fb, fb] ----
    float creg[4][4];
#pragma unroll
    for (int mi = 0; mi < 4; ++mi)
#pragma unroll
        for (int r = 0; r < 4; ++r) {
            int m = m0 + mi * 16 + quad * 4 + r;
            creg[mi][r] = (float)encb[((size_t)1 * NB + m) * 1024 + 512 + (c & 511)];
            hseq[(size_t)m * HD + c] = encb[((size_t)1 * NB + m) * 1024 + c];
        }
    if (bi == 0 && tid < NB)
        __hip_atomic_store(idx + tid, -1, __ATOMIC_RELAXED, __HIP_MEMORY_SCOPE_AGENT);

    // ---- hoisted gate-phase constants ----
    const bf16_t* brow[4];
#pragma unroll
    for (int g4 = 0; g4 < 4; ++g4) brow[g4] = whh + (size_t)(g4 * 1024 + c0 + l15) * 1024;
    float bv[4];
#pragma unroll
    for (int g4 = 0; g4 < 4; ++g4) bv[g4] = bias[g4 * 1024 + c];
    size_t aoff[4];
#pragma unroll
    for (int mi = 0; mi < 4; ++mi) aoff[mi] = (size_t)(m0 + mi * 16 + l15) * 1024;

    // ---- hoisted logits constants (wave handles batch b = ct) ----
    const int b = ct;
    const float4* wl0 = (const float4*)(out_w + (size_t)lane * HD);
    const float4* wl1 = (const float4*)(out_w + (size_t)(lane + 64) * HD);
    const float ob0 = out_b[lane], ob1 = out_b[lane + 64];
    float loss_acc = 0.0f;

    gbar(bars, bidx, 32);

    for (int t = 0; t < LQ; ++t) {
        // ================= phase A: gates + cell =================
        const bf16_t* hin = hseq + (size_t)t * (NB * HD);

        // hoist idx reads (coherent-point loads, hidden under the GEMM)
        int idr[4][4];
#pragma unroll
        for (int mi = 0; mi < 4; ++mi)
#pragma unroll
            for (int r = 0; r < 4; ++r) {
                int m = m0 + mi * 16 + quad * 4 + r;
                idr[mi][r] = __hip_atomic_load(idx + m, __ATOMIC_RELAXED,
                                               __HIP_MEMORY_SCOPE_AGENT);
            }

        f32x4 acc[4][4] = {};
        for (int kb = 0; kb < 1024; kb += 32) {
            bf16x8 af[4], bfr[4];
#pragma unroll
            for (int mi = 0; mi < 4; ++mi) af[mi] = ldf(hin + aoff[mi] + kb + quad * 8);
#pragma unroll
            for (int g4 = 0; g4 < 4; ++g4) bfr[g4] = ldf(brow[g4] + kb + quad * 8);
#pragma unroll
            for (int mi = 0; mi < 4; ++mi)
#pragma unroll
                for (int g4 = 0; g4 < 4; ++g4)
                    acc[mi][g4] = mfma16(af[mi], bfr[g4], acc[mi][g4]);
        }

        bf16_t* wnext = hseq + (size_t)(t + 1) * (NB * HD);
#pragma unroll
        for (int mi = 0; mi < 4; ++mi)
#pragma unroll
            for (int r = 0; r < 4; ++r) {
                int m = m0 + mi * 16 + quad * 4 + r;
                int id = idr[mi][r];
                float gv[4];
#pragma unroll
                for (int g4 = 0; g4 < 4; ++g4) {
                    float wi = (id >= 0) ? wih[(size_t)(g4 * 1024 + c) * TT + id] : 0.0f;
                    gv[g4] = acc[mi][g4][r] + bv[g4] + wi;
                }
                float cn = sigf(gv[1]) * creg[mi][r] + sigf(gv[0]) * tanhf(gv[2]);
                float hn = sigf(gv[3]) * tanhf(cn);
                creg[mi][r] = cn;
                hdec[(size_t)m * HD + c] = hn;
                if (t + 1 < LQ)
                    wnext[(size_t)m * HD + c] =
                        (bf16_t)(hn + (float)encb[((size_t)(t + 2) * NB + m) * 1024 + c]);
            }
        gbar(bars, bidx, 32);

        // ================= phase B: logits / softmax / argmax / loss =======
        // stage hdec row b via coherent-point u32 loads, lane-stride-1
        float* hr = hrow + (size_t)w * HD;
        const unsigned* hsrc = (const unsigned*)(hdec + (size_t)b * HD);
#pragma unroll
        for (int k = 0; k < 16; ++k) {
            unsigned v = __hip_atomic_load(hsrc + lane + k * 64, __ATOMIC_RELAXED,
                                           __HIP_MEMORY_SCOPE_AGENT);
            ((unsigned*)hr)[lane + k * 64] = v;
        }
        __syncthreads();

        float a0 = ob0, a1 = ob1;
        for (int k = 0; k < HD / 4; ++k) {
            float4 h4 = ((const float4*)hr)[k];
            float4 x0 = wl0[k];
            float4 x1 = wl1[k];
            a0 += h4.x * x0.x + h4.y * x0.y + h4.z * x0.z + h4.w * x0.w;
            a1 += h4.x * x1.x + h4.y * x1.y + h4.z * x1.z + h4.w * x1.w;
        }
        float mx = fmaxf(a0, a1);
#pragma unroll
        for (int off2 = 32; off2 > 0; off2 >>= 1) mx = fmaxf(mx, __shfl_xor(mx, off2));
        float sm = __expf(a0 - mx) + __expf(a1 - mx);
#pragma unroll
        for (int off2 = 32; off2 > 0; off2 >>= 1) sm += __shfl_xor(sm, off2);
        float lse = mx + logf(sm);
        size_t pbase = (size_t)b * (LQ * TT) + (size_t)t * TT;
        prob_out[pbase + lane] = __expf(a0 - lse);
        prob_out[pbase + lane + 64] = __expf(a1 - lse);

        // first-max argmax (smaller index wins ties)
        float bvv;
        int bix;
        if (a1 > a0) { bvv = a1; bix = lane + 64; } else { bvv = a0; bix = lane; }
#pragma unroll
        for (int off2 = 32; off2 > 0; off2 >>= 1) {
            float ov = __shfl_xor(bvv, off2);
            int oi = __shfl_xor(bix, off2);
            if (ov > bvv || (ov == bvv && oi < bix)) { bvv = ov; bix = oi; }
        }
        if (lane == 0)
            __hip_atomic_store(idx + b, bix, __ATOMIC_RELAXED,
                               __HIP_MEMORY_SCOPE_AGENT);

        int tg = tags[b * LQ + t];
        float l0 = __shfl(a0, tg & 63);
        float l1 = __shfl(a1, tg & 63);
        float lv = (tg >= 64) ? l1 : l0;
        if (lane == 0) loss_acc += -(lv - lse) * (1.0f / 128.0f);
        gbar(bars, bidx, 32);
    }
    if (lane == 0) atomicAdd(loss_out, loss_acc);
}

// ---------------------------------------------------------------------------
extern "C" void kernel_launch(void* const* d_in, const int* in_sizes, int n_in,
                              void* d_out, int out_size, void* d_ws, size_t ws_size,
                              hipStream_t stream) {
    (void)in_sizes; (void)n_in; (void)out_size;
    const int*   ids    = (const int*)d_in[0];
    const int*   tags   = (const int*)d_in[1];
    const float* embed  = (const float*)d_in[2];
    const float* e0_wih = (const float*)d_in[3];
    const float* e0_whh = (const float*)d_in[4];
    const float* e0_b   = (const float*)d_in[5];
    const float* e1_wih = (const float*)d_in[6];
    const float* e1_whh = (const float*)d_in[7];
    const float* e1_b   = (const float*)d_in[8];
    const float* d_wih  = (const float*)d_in[9];
    const float* d_whh  = (const float*)d_in[10];
    const float* d_b    = (const float*)d_in[11];
    const float* out_w  = (const float*)d_in[12];
    const float* out_b  = (const float*)d_in[13];
    float* prob = (float*)d_out;

    char* ws = (char*)d_ws;
    size_t off = 0;
    auto alloc = [&](size_t bytes) -> void* {
        void* p = ws + off;
        off += (bytes + 255) & ~(size_t)255;
        return p;
    };
    // bf16 weights (~28 MiB; embed stays f32, converted in-register in xg0):
    bf16_t* e0wihB = (bf16_t*)alloc((size_t)2 * 2048 * 512 * 2);
    bf16_t* e0whhB = (bf16_t*)alloc((size_t)2 * 2048 * 512 * 2);
    bf16_t* e1wihB = (bf16_t*)alloc((size_t)2 * 2048 * 1024 * 2);
    bf16_t* e1whhB = (bf16_t*)alloc((size_t)2 * 2048 * 512 * 2);
    bf16_t* dwhhB  = (bf16_t*)alloc((size_t)4096 * 1024 * 2);
    // per-timestep state rings (~125 MiB):
    bf16_t* h1    = (bf16_t*)alloc((size_t)(LQ + 2) * NB * 1024 * 2);  // enc0 ring
    bf16_t* encb  = (bf16_t*)alloc((size_t)(LQ + 2) * NB * 1024 * 2);  // enc1 ring
    bf16_t* hseqD = (bf16_t*)alloc((size_t)LQ * NB * HD * 2);          // decoder ring
    float*  cstE  = (float*)alloc((size_t)2 * 2 * NB * 512 * 4);       // [layer][dir][N][HE]
    float*  hdec  = (float*)alloc((size_t)NB * HD * 4);
    int*    idx   = (int*)alloc(NB * 4);
    // barrier sets: 1024 instances x 8 lines x 64 B = 512 KB, pre-zeroed.
    unsigned* bars = (unsigned*)alloc((size_t)1024 * BAR_STRIDE * 4);
    size_t fixed_end = off;

    // Step-chunked input-projection gate buffer, sized from ws_size.
    static const int ch_opts[] = {40, 32, 20, 16, 10, 8, 5, 4, 2, 1};
    int CH = 1;
    for (int i = 0; i < 10; ++i) {
        size_t need = (size_t)ch_opts[i] * NB * 4096 * 2;
        if (fixed_end + need <= ws_size) { CH = ch_opts[i]; break; }
    }
    bf16_t* xgc = (bf16_t*)alloc((size_t)CH * NB * 4096 * 2);

    // ---- one-time weight conversion ----
    auto cvt = [&](const float* s, bf16_t* d, size_t n) {
        int n4 = (int)(n / 4);
        k_cvt<<<dim3((n4 + 255) / 256), 256, 0, stream>>>(s, d, n4);
    };
    cvt(e0_wih, e0wihB, (size_t)2 * 2048 * 512);
    cvt(e0_whh, e0whhB, (size_t)2 * 2048 * 512);
    cvt(e1_wih, e1wihB, (size_t)2 * 2048 * 1024);
    cvt(e1_whh, e1whhB, (size_t)2 * 2048 * 512);
    cvt(d_whh, dwhhB, (size_t)4096 * 1024);

    const size_t SLOT = (size_t)NB * 1024;  // ring slot elems
    hipMemsetAsync(h1, 0, SLOT * 2, stream);                            // slot 0
    hipMemsetAsync(h1 + (size_t)(LQ + 1) * SLOT, 0, SLOT * 2, stream);  // slot LQ+1
    hipMemsetAsync(encb, 0, SLOT * 2, stream);
    hipMemsetAsync(encb + (size_t)(LQ + 1) * SLOT, 0, SLOT * 2, stream);
    hipMemsetAsync(cstE, 0, (size_t)2 * 2 * NB * 512 * 4, stream);
    hipMemsetAsync(bars, 0, (size_t)1024 * BAR_STRIDE * 4, stream);
    hipMemsetAsync(prob + (size_t)NB * LQ * TT, 0, 4, stream);  // loss scalar

    // barrier-set regions: enc0 chunk cc -> sets [cc*CH ..], enc1 -> LQ + cc*CH,
    // decoder -> 2*LQ .. (needs 1 + 2*LQ = 321 sets; 1024 allocated)
    // ---- encoder layer 0 ----
    for (int cc = 0; cc < LQ / CH; ++cc) {
        int s0 = cc * CH;
        k_xg0c<<<dim3(CH * 2, 32, 2), 64, 0, stream>>>(ids, embed, e0wihB, xgc, s0);
        k_enc_chunk<<<dim3(32), 256, 0, stream>>>(h1, e0whhB, e0_b, xgc, cstE,
                                                  bars + (size_t)(cc * CH) * BAR_STRIDE,
                                                  s0, CH);
    }
    // ---- encoder layer 1 ----
    for (int cc = 0; cc < LQ / CH; ++cc) {
        int s0 = cc * CH;
        k_xg1c<<<dim3(CH * 2, 32, 2), 64, 0, stream>>>(h1, e1wihB, xgc, s0);
        k_enc_chunk<<<dim3(32), 256, 0, stream>>>(encb, e1whhB, e1_b, xgc,
                                                  cstE + (size_t)2 * NB * 512,
                                                  bars + (size_t)(LQ + cc * CH) * BAR_STRIDE,
                                                  s0, CH);
    }
    // ---- decoder (one persistent launch) ----
    k_dec_persist<<<dim3(32), 256, 0, stream>>>(encb, dwhhB, d_b, d_wih, out_w, out_b,
                                                tags, hseqD, hdec, idx,
                                                bars + (size_t)(2 * LQ) * BAR_STRIDE,
                                                prob, prob + (size_t)NB * LQ * TT);
}

// Round 5
// 22268.394 us; speedup vs baseline: 1.2759x; 1.2759x over previous
//
#include <hip/hip_runtime.h>

// ---------------------------------------------------------------------------
// FocusModel: embed -> bidir LSTM (E=512->HE=512) -> bidir LSTM (1024->512)
//          -> decoder LSTM (HD=1024, one-hot argmax feedback) -> softmax/loss
// R8: R7 confounded two changes: distributed barrier (good) + 32x256 topology
// (bad: 1/4 aggregate L1/LSU capacity for a latency-bound workload -> 119
// us/step). R8 isolates the barrier fix at R6's proven topology:
//   - 128 blocks x 64 threads (1 wave/CU) everywhere persistent (as R6).
//   - distributed generation-free barrier: 16 cache-line counters per
//     instance; arrival = RELEASE fetch_add on line (bi&15) (<=8 serialized
//     RMWs/line); wait = lanes 0-15 poll 16 lines, butterfly-sum >= 128.
//     No acquire, no reset, no buffer_inv (R6's ring-fresh addressing and
//     agent-scope atomic loads carry cross-XCD visibility).
//   - phase-B staging via u32 lane-stride-1 atomic loads (0 bank conflicts).
// Math identical to the verified R3/R5/R6 kernels.
// ---------------------------------------------------------------------------

typedef __bf16 bf16_t;
typedef __bf16 bf16x8 __attribute__((ext_vector_type(8)));
typedef __bf16 bf16x4 __attribute__((ext_vector_type(4)));
typedef float  f32x4  __attribute__((ext_vector_type(4)));

#define NB 128
#define LQ 160
#define EE 512
#define HE 512
#define HD 1024
#define TT 128

__device__ __forceinline__ f32x4 mfma16(bf16x8 a, bf16x8 b, f32x4 c) {
    return __builtin_amdgcn_mfma_f32_16x16x32_bf16(a, b, c, 0, 0, 0);
}
__device__ __forceinline__ bf16x8 ldf(const bf16_t* p) { return *(const bf16x8*)p; }
__device__ __forceinline__ float sigf(float x) { return 1.0f / (1.0f + __expf(-x)); }

// 8 f32 -> bf16x8 (RNE, same numerics as k_cvt).
__device__ __forceinline__ bf16x8 cvt8(const float* p) {
    float4 f0 = ((const float4*)p)[0];
    float4 f1 = ((const float4*)p)[1];
    bf16x8 a;
    a[0] = (bf16_t)f0.x; a[1] = (bf16_t)f0.y; a[2] = (bf16_t)f0.z; a[3] = (bf16_t)f0.w;
    a[4] = (bf16_t)f1.x; a[5] = (bf16_t)f1.y; a[6] = (bf16_t)f1.z; a[7] = (bf16_t)f1.w;
    return a;
}

// ---------------------------------------------------------------------------
// Distributed grid barrier, generation-free. Each barrier instance owns 16
// cache lines (16 x 16 u32 = 1 KiB), pre-zeroed once on the host. Arrival:
// RELEASE fetch_add on line (blockIdx&15) -> drains vmcnt + writes back dirty
// L2 (producers' stores reach the coherent point); <=8 serialized RMWs/line,
// 16 lines in parallel. Wait: lanes 0-15 poll the 16 lines (relaxed agent
// loads), butterfly-sum; s_sleep backoff cuts poll pressure on the lines.
// Works for single-wave blocks: the release atomic itself orders prior
// stores (compiler emits s_waitcnt vmcnt(0) before it).
// ---------------------------------------------------------------------------
#define BAR_STRIDE 256  // u32s per barrier instance (16 lines x 16 u32)
__device__ __forceinline__ void gbar(unsigned* __restrict__ bars, int& bidx,
                                     unsigned nblk) {
    unsigned* lines = bars + (size_t)bidx * BAR_STRIDE;
    __syncthreads();
    if (threadIdx.x == 0)
        __hip_atomic_fetch_add(lines + (blockIdx.x & 15) * 16, 1u,
                               __ATOMIC_RELEASE, __HIP_MEMORY_SCOPE_AGENT);
    if (threadIdx.x < 16) {
        for (;;) {
            unsigned s = __hip_atomic_load(lines + threadIdx.x * 16,
                                           __ATOMIC_RELAXED,
                                           __HIP_MEMORY_SCOPE_AGENT);
            s += __shfl_xor(s, 1);
            s += __shfl_xor(s, 2);
            s += __shfl_xor(s, 4);
            s += __shfl_xor(s, 8);
            if (s >= nblk) break;
            __builtin_amdgcn_s_sleep(2);
        }
    }
    __syncthreads();
    ++bidx;
}

// f32 -> bf16 bulk convert (n4 = n/4, all sizes divisible by 4).
__global__ __launch_bounds__(256) void k_cvt(const float* __restrict__ src,
                                             bf16_t* __restrict__ dst, int n4) {
    int i = blockIdx.x * 256 + threadIdx.x;
    if (i < n4) {
        float4 v = ((const float4*)src)[i];
        bf16x4 o;
        o[0] = (bf16_t)v.x; o[1] = (bf16_t)v.y; o[2] = (bf16_t)v.z; o[3] = (bf16_t)v.w;
        ((bf16x4*)dst)[i] = o;
    }
}

// ---------------------------------------------------------------------------
// Chunked input projection, layer 0. Rows m = (s-s0)*128 + b; per-direction
// source timestep t = d ? L-1-s : s; A-row = embed[ids[b][t]] (f32 gather,
// converted in-register). grid (CH*2, 32, 2), block 64.
// ---------------------------------------------------------------------------
__global__ __launch_bounds__(64) void k_xg0c(const int* __restrict__ ids,
                                             const float* __restrict__ embed,
                                             const bf16_t* __restrict__ wih,
                                             bf16_t* __restrict__ xgc,
                                             int s0) {
    const int lane = threadIdx.x;
    const int l15 = lane & 15, quad = lane >> 4;
    const int m0 = blockIdx.x * 64;
    const int n0 = blockIdx.y * 64;
    const int d  = blockIdx.z;
    const bf16_t* Wd = wih + (size_t)d * 2048 * 512;

    const float* arow[4];
#pragma unroll
    for (int mi = 0; mi < 4; ++mi) {
        int m = m0 + mi * 16 + l15;
        int b = m & 127, s = s0 + (m >> 7);
        int t = d ? (LQ - 1 - s) : s;
        int id = ids[b * LQ + t];
        arow[mi] = embed + (size_t)id * EE;
    }
    const bf16_t* brow[4];
#pragma unroll
    for (int ni = 0; ni < 4; ++ni) brow[ni] = Wd + (size_t)(n0 + ni * 16 + l15) * 512;

    f32x4 acc[4][4] = {};
    for (int kb = 0; kb < 512; kb += 32) {
        bf16x8 af[4], bfr[4];
#pragma unroll
        for (int mi = 0; mi < 4; ++mi) af[mi] = cvt8(arow[mi] + kb + quad * 8);
#pragma unroll
        for (int ni = 0; ni < 4; ++ni) bfr[ni] = ldf(brow[ni] + kb + quad * 8);
#pragma unroll
        for (int mi = 0; mi < 4; ++mi)
#pragma unroll
            for (int ni = 0; ni < 4; ++ni)
                acc[mi][ni] = mfma16(af[mi], bfr[ni], acc[mi][ni]);
    }
#pragma unroll
    for (int mi = 0; mi < 4; ++mi)
#pragma unroll
        for (int ni = 0; ni < 4; ++ni)
#pragma unroll
            for (int r = 0; r < 4; ++r) {
                int m = m0 + mi * 16 + quad * 4 + r;
                int n = n0 + ni * 16 + l15;
                xgc[(size_t)m * 4096 + d * 2048 + n] = (bf16_t)acc[mi][ni][r];
            }
}

// Chunked input projection, layer 1: A-row = h1ring[1+t][b] (1024 wide), K=1024.
__global__ __launch_bounds__(64) void k_xg1c(const bf16_t* __restrict__ h1,
                                             const bf16_t* __restrict__ wih,
                                             bf16_t* __restrict__ xgc,
                                             int s0) {
    const int lane = threadIdx.x;
    const int l15 = lane & 15, quad = lane >> 4;
    const int m0 = blockIdx.x * 64;
    const int n0 = blockIdx.y * 64;
    const int d  = blockIdx.z;
    const bf16_t* Wd = wih + (size_t)d * 2048 * 1024;

    const bf16_t* arow[4];
#pragma unroll
    for (int mi = 0; mi < 4; ++mi) {
        int m = m0 + mi * 16 + l15;
        int b = m & 127, s = s0 + (m >> 7);
        int t = d ? (LQ - 1 - s) : s;
        arow[mi] = h1 + ((size_t)(1 + t) * NB + b) * 1024;
    }
    const bf16_t* brow[4];
#pragma unroll
    for (int ni = 0; ni < 4; ++ni) brow[ni] = Wd + (size_t)(n0 + ni * 16 + l15) * 1024;

    f32x4 acc[4][4] = {};
    for (int kb = 0; kb < 1024; kb += 32) {
        bf16x8 af[4], bfr[4];
#pragma unroll
        for (int mi = 0; mi < 4; ++mi) af[mi] = ldf(arow[mi] + kb + quad * 8);
#pragma unroll
        for (int ni = 0; ni < 4; ++ni) bfr[ni] = ldf(brow[ni] + kb + quad * 8);
#pragma unroll
        for (int mi = 0; mi < 4; ++mi)
#pragma unroll
            for (int ni = 0; ni < 4; ++ni)
                acc[mi][ni] = mfma16(af[mi], bfr[ni], acc[mi][ni]);
    }
#pragma unroll
    for (int mi = 0; mi < 4; ++mi)
#pragma unroll
        for (int ni = 0; ni < 4; ++ni)
#pragma unroll
            for (int r = 0; r < 4; ++r) {
                int m = m0 + mi * 16 + quad * 4 + r;
                int n = n0 + ni * 16 + l15;
                xgc[(size_t)m * 4096 + d * 2048 + n] = (bf16_t)acc[mi][ni][r];
            }
}

// ---------------------------------------------------------------------------
// Persistent encoder chunk. 128 blocks x 64 thr; block bi -> m-block (bi&1),
// col-block ((bi>>1)&31), dir (bi>>6). Recurrent h read/written directly in
// the per-timestep ring hring[1+t][b][d*512+c] (slots 0, LQ+1 zeroed).
// Cell state in registers across the chunk; persisted to cst between chunks.
// ---------------------------------------------------------------------------
__global__ __launch_bounds__(64) void k_enc_chunk(bf16_t* __restrict__ hring,
                                                  const bf16_t* __restrict__ whh,
                                                  const float* __restrict__ bias,
                                                  const bf16_t* __restrict__ xgc,
                                                  float* __restrict__ cst,
                                                  unsigned* __restrict__ bars,
                                                  int s0, int nsteps) {
    const int lane = threadIdx.x;
    const int l15 = lane & 15, quad = lane >> 4;
    const int bi = blockIdx.x;
    const int m0 = (bi & 1) * 64;
    const int c0 = ((bi >> 1) & 31) * 16;
    const int d  = bi >> 6;
    int bidx = 0;

    const bf16_t* Wd = whh + (size_t)d * 2048 * 512;
    const bf16_t* brow[4];
#pragma unroll
    for (int g4 = 0; g4 < 4; ++g4) brow[g4] = Wd + (size_t)(g4 * 512 + c0 + l15) * 512;
    const int c = c0 + l15;
    float bv[4];
#pragma unroll
    for (int g4 = 0; g4 < 4; ++g4) bv[g4] = bias[d * 2048 + g4 * 512 + c];
    size_t aoff[4];
#pragma unroll
    for (int mi = 0; mi < 4; ++mi) aoff[mi] = (size_t)(m0 + mi * 16 + l15) * 1024;

    // cell state in registers (block ownership constant across steps)
    float creg[4][4];
#pragma unroll
    for (int mi = 0; mi < 4; ++mi)
#pragma unroll
        for (int r = 0; r < 4; ++r) {
            int m = m0 + mi * 16 + quad * 4 + r;
            creg[mi][r] = cst[((size_t)d * NB + m) * 512 + c];
        }

    for (int s = s0; s < s0 + nsteps; ++s) {
        const int t     = d ? (LQ - 1 - s) : s;
        const int tprev = d ? (LQ - s)     : (s - 1);
        const bf16_t* abase = hring + ((size_t)(1 + tprev) * NB) * 1024 + (size_t)d * 512;

        f32x4 acc[4][4] = {};  // [mi][gate]
        for (int kb = 0; kb < 512; kb += 32) {
            bf16x8 af[4], bfr[4];
#pragma unroll
            for (int mi = 0; mi < 4; ++mi) af[mi] = ldf(abase + aoff[mi] + kb + quad * 8);
#pragma unroll
            for (int g4 = 0; g4 < 4; ++g4) bfr[g4] = ldf(brow[g4] + kb + quad * 8);
#pragma unroll
            for (int mi = 0; mi < 4; ++mi)
#pragma unroll
                for (int g4 = 0; g4 < 4; ++g4)
                    acc[mi][g4] = mfma16(af[mi], bfr[g4], acc[mi][g4]);
        }

        bf16_t* wbase = hring + ((size_t)(1 + t) * NB) * 1024 + (size_t)d * 512;
#pragma unroll
        for (int mi = 0; mi < 4; ++mi)
#pragma unroll
            for (int r = 0; r < 4; ++r) {
                int m = m0 + mi * 16 + quad * 4 + r;
                size_t xoff = ((size_t)(s - s0) * NB + m) * 4096 + (size_t)d * 2048;
                float gi = acc[mi][0][r] + (float)xgc[xoff + 0 * 512 + c] + bv[0];
                float gf = acc[mi][1][r] + (float)xgc[xoff + 1 * 512 + c] + bv[1];
                float gg = acc[mi][2][r] + (float)xgc[xoff + 2 * 512 + c] + bv[2];
                float go = acc[mi][3][r] + (float)xgc[xoff + 3 * 512 + c] + bv[3];
                float cn = sigf(gf) * creg[mi][r] + sigf(gi) * tanhf(gg);
                float hn = sigf(go) * tanhf(cn);
                creg[mi][r] = cn;
                wbase[(size_t)m * 1024 + c] = (bf16_t)hn;
            }
        if (s + 1 < s0 + nsteps) gbar(bars, bidx, 128);
    }

#pragma unroll
    for (int mi = 0; mi < 4; ++mi)
#pragma unroll
        for (int r = 0; r < 4; ++r) {
            int m = m0 + mi * 16 + quad * 4 + r;
            cst[((size_t)d * NB + m) * 512 + c] = creg[mi][r];
        }
}

// ---------------------------------------------------------------------------
// Persistent decoder: init + 160 steps, 128 blocks x 64 thr.
// Phase A: gate GEMM (h from ring hseq[t], writes hseq[t+1] = h + enc[t+1])
//   + cell math (cell state in regs), hdec (f32) for logits. -> gbar
// Phase B: block bi = batch b; lane n computes tags n and n+64; hdec row
//   staged to LDS via u32 agent atomic loads (lane-stride-1, conflict-free);
//   shuffle softmax / first-max argmax / in-register loss. -> gbar
// ---------------------------------------------------------------------------
__global__ __launch_bounds__(64) void k_dec_persist(const bf16_t* __restrict__ encb,
                                                    const bf16_t* __restrict__ whh,
                                                    const float* __restrict__ bias,
                                                    const float* __restrict__ wih,
                                                    const float* __restrict__ out_w,
                                                    const float* __restrict__ out_b,
                                                    const int* __restrict__ tags,
                                                    bf16_t* __restrict__ hseq,
                                                    float* __restrict__ hdec,
                                                    int* __restrict__ idx,
                                                    unsigned* __restrict__ bars,
                                                    float* __restrict__ prob_out,
                                                    float* __restrict__ loss_out) {
    const int lane = threadIdx.x;
    const int bi = blockIdx.x;
    const int l15 = lane & 15, quad = lane >> 4;
    const int m0 = (bi & 1) * 64;
    const int c0 = (bi >> 1) * 16;
    const int c = c0 + l15;
    int bidx = 0;
    __shared__ float hrow[HD];

    // ---- init own tile: hseq[0] = enc[0] (ring slot 1), c0 = [fb, fb] ----
    float creg[4][4];
#pragma unroll
    for (int mi = 0; mi < 4; ++mi)
#pragma unroll
        for (int r = 0; r < 4; ++r) {
            int m = m0 + mi * 16 + quad * 4 + r;
            creg[mi][r] = (float)encb[((size_t)1 * NB + m) * 1024 + 512 + (c & 511)];
            hseq[(size_t)m * HD + c] = encb[((size_t)1 * NB + m) * 1024 + c];
        }
    if (bi < 2)
        __hip_atomic_store(idx + bi * 64 + lane, -1, __ATOMIC_RELAXED,
                           __HIP_MEMORY_SCOPE_AGENT);

    // ---- hoisted gate-phase constants ----
    const bf16_t* brow[4];
#pragma unroll
    for (int g4 = 0; g4 < 4; ++g4) brow[g4] = whh + (size_t)(g4 * 1024 + c0 + l15) * 1024;
    float bv[4];
#pragma unroll
    for (int g4 = 0; g4 < 4; ++g4) bv[g4] = bias[g4 * 1024 + c];
    size_t aoff[4];
#pragma unroll
    for (int mi = 0; mi < 4; ++mi) aoff[mi] = (size_t)(m0 + mi * 16 + l15) * 1024;

    // ---- hoisted logits constants (block bi = batch b) ----
    const int b = bi;
    const float4* wl0 = (const float4*)(out_w + (size_t)lane * HD);
    const float4* wl1 = (const float4*)(out_w + (size_t)(lane + 64) * HD);
    const float ob0 = out_b[lane], ob1 = out_b[lane + 64];
    float loss_acc = 0.0f;

    gbar(bars, bidx, 128);

    for (int t = 0; t < LQ; ++t) {
        // ================= phase A: gates + cell =================
        const bf16_t* hin = hseq + (size_t)t * (NB * HD);

        // hoist idx reads (coherent-point loads, hidden under the GEMM)
        int idr[4][4];
#pragma unroll
        for (int mi = 0; mi < 4; ++mi)
#pragma unroll
            for (int r = 0; r < 4; ++r) {
                int m = m0 + mi * 16 + quad * 4 + r;
                idr[mi][r] = __hip_atomic_load(idx + m, __ATOMIC_RELAXED,
                                               __HIP_MEMORY_SCOPE_AGENT);
            }

        f32x4 acc[4][4] = {};
        for (int kb = 0; kb < 1024; kb += 32) {
            bf16x8 af[4], bfr[4];
#pragma unroll
            for (int mi = 0; mi < 4; ++mi) af[mi] = ldf(hin + aoff[mi] + kb + quad * 8);
#pragma unroll
            for (int g4 = 0; g4 < 4; ++g4) bfr[g4] = ldf(brow[g4] + kb + quad * 8);
#pragma unroll
            for (int mi = 0; mi < 4; ++mi)
#pragma unroll
                for (int g4 = 0; g4 < 4; ++g4)
                    acc[mi][g4] = mfma16(af[mi], bfr[g4], acc[mi][g4]);
        }

        bf16_t* wnext = hseq + (size_t)(t + 1) * (NB * HD);
#pragma unroll
        for (int mi = 0; mi < 4; ++mi)
#pragma unroll
            for (int r = 0; r < 4; ++r) {
                int m = m0 + mi * 16 + quad * 4 + r;
                int id = idr[mi][r];
                float gv[4];
#pragma unroll
                for (int g4 = 0; g4 < 4; ++g4) {
                    float wi = (id >= 0) ? wih[(size_t)(g4 * 1024 + c) * TT + id] : 0.0f;
                    gv[g4] = acc[mi][g4][r] + bv[g4] + wi;
                }
                float cn = sigf(gv[1]) * creg[mi][r] + sigf(gv[0]) * tanhf(gv[2]);
                float hn = sigf(gv[3]) * tanhf(cn);
                creg[mi][r] = cn;
                hdec[(size_t)m * HD + c] = hn;
                if (t + 1 < LQ)
                    wnext[(size_t)m * HD + c] =
                        (bf16_t)(hn + (float)encb[((size_t)(t + 2) * NB + m) * 1024 + c]);
            }
        gbar(bars, bidx, 128);

        // ================= phase B: logits / softmax / argmax / loss =======
        // stage hdec row b via coherent-point u32 loads, lane-stride-1
        const unsigned* hsrc = (const unsigned*)(hdec + (size_t)b * HD);
#pragma unroll
        for (int k = 0; k < 16; ++k) {
            unsigned v = __hip_atomic_load(hsrc + lane + k * 64, __ATOMIC_RELAXED,
                                           __HIP_MEMORY_SCOPE_AGENT);
            ((unsigned*)hrow)[lane + k * 64] = v;
        }
        __syncthreads();

        float a0 = ob0, a1 = ob1;
        for (int k = 0; k < HD / 4; ++k) {
            float4 h4 = ((const float4*)hrow)[k];
            float4 x0 = wl0[k];
            float4 x1 = wl1[k];
            a0 += h4.x * x0.x + h4.y * x0.y + h4.z * x0.z + h4.w * x0.w;
            a1 += h4.x * x1.x + h4.y * x1.y + h4.z * x1.z + h4.w * x1.w;
        }
        float mx = fmaxf(a0, a1);
#pragma unroll
        for (int off2 = 32; off2 > 0; off2 >>= 1) mx = fmaxf(mx, __shfl_xor(mx, off2));
        float sm = __expf(a0 - mx) + __expf(a1 - mx);
#pragma unroll
        for (int off2 = 32; off2 > 0; off2 >>= 1) sm += __shfl_xor(sm, off2);
        float lse = mx + logf(sm);
        size_t pbase = (size_t)b * (LQ * TT) + (size_t)t * TT;
        prob_out[pbase + lane] = __expf(a0 - lse);
        prob_out[pbase + lane + 64] = __expf(a1 - lse);

        // first-max argmax (smaller index wins ties)
        float bvv;
        int bix;
        if (a1 > a0) { bvv = a1; bix = lane + 64; } else { bvv = a0; bix = lane; }
#pragma unroll
        for (int off2 = 32; off2 > 0; off2 >>= 1) {
            float ov = __shfl_xor(bvv, off2);
            int oi = __shfl_xor(bix, off2);
            if (ov > bvv || (ov == bvv && oi < bix)) { bvv = ov; bix = oi; }
        }
        if (lane == 0)
            __hip_atomic_store(idx + b, bix, __ATOMIC_RELAXED,
                               __HIP_MEMORY_SCOPE_AGENT);

        int tg = tags[b * LQ + t];
        float l0 = __shfl(a0, tg & 63);
        float l1 = __shfl(a1, tg & 63);
        float lv = (tg >= 64) ? l1 : l0;
        if (lane == 0) loss_acc += -(lv - lse) * (1.0f / 128.0f);
        gbar(bars, bidx, 128);
    }
    if (lane == 0) atomicAdd(loss_out, loss_acc);
}

// ---------------------------------------------------------------------------
extern "C" void kernel_launch(void* const* d_in, const int* in_sizes, int n_in,
                              void* d_out, int out_size, void* d_ws, size_t ws_size,
                              hipStream_t stream) {
    (void)in_sizes; (void)n_in; (void)out_size;
    const int*   ids    = (const int*)d_in[0];
    const int*   tags   = (const int*)d_in[1];
    const float* embed  = (const float*)d_in[2];
    const float* e0_wih = (const float*)d_in[3];
    const float* e0_whh = (const float*)d_in[4];
    const float* e0_b   = (const float*)d_in[5];
    const float* e1_wih = (const float*)d_in[6];
    const float* e1_whh = (const float*)d_in[7];
    const float* e1_b   = (const float*)d_in[8];
    const float* d_wih  = (const float*)d_in[9];
    const float* d_whh  = (const float*)d_in[10];
    const float* d_b    = (const float*)d_in[11];
    const float* out_w  = (const float*)d_in[12];
    const float* out_b  = (const float*)d_in[13];
    float* prob = (float*)d_out;

    char* ws = (char*)d_ws;
    size_t off = 0;
    auto alloc = [&](size_t bytes) -> void* {
        void* p = ws + off;
        off += (bytes + 255) & ~(size_t)255;
        return p;
    };
    // bf16 weights (~28 MiB; embed stays f32, converted in-register in xg0):
    bf16_t* e0wihB = (bf16_t*)alloc((size_t)2 * 2048 * 512 * 2);
    bf16_t* e0whhB = (bf16_t*)alloc((size_t)2 * 2048 * 512 * 2);
    bf16_t* e1wihB = (bf16_t*)alloc((size_t)2 * 2048 * 1024 * 2);
    bf16_t* e1whhB = (bf16_t*)alloc((size_t)2 * 2048 * 512 * 2);
    bf16_t* dwhhB  = (bf16_t*)alloc((size_t)4096 * 1024 * 2);
    // per-timestep state rings (~125 MiB):
    bf16_t* h1    = (bf16_t*)alloc((size_t)(LQ + 2) * NB * 1024 * 2);  // enc0 ring
    bf16_t* encb  = (bf16_t*)alloc((size_t)(LQ + 2) * NB * 1024 * 2);  // enc1 ring
    bf16_t* hseqD = (bf16_t*)alloc((size_t)LQ * NB * HD * 2);          // decoder ring
    float*  cstE  = (float*)alloc((size_t)2 * 2 * NB * 512 * 4);       // [layer][dir][N][HE]
    float*  hdec  = (float*)alloc((size_t)NB * HD * 4);
    int*    idx   = (int*)alloc(NB * 4);
    // barrier sets: 1024 instances x 16 lines x 64 B = 1 MiB, pre-zeroed.
    unsigned* bars = (unsigned*)alloc((size_t)1024 * BAR_STRIDE * 4);
    size_t fixed_end = off;

    // Step-chunked input-projection gate buffer, sized from ws_size.
    static const int ch_opts[] = {40, 32, 20, 16, 10, 8, 5, 4, 2, 1};
    int CH = 1;
    for (int i = 0; i < 10; ++i) {
        size_t need = (size_t)ch_opts[i] * NB * 4096 * 2;
        if (fixed_end + need <= ws_size) { CH = ch_opts[i]; break; }
    }
    bf16_t* xgc = (bf16_t*)alloc((size_t)CH * NB * 4096 * 2);

    // ---- one-time weight conversion ----
    auto cvt = [&](const float* s, bf16_t* d, size_t n) {
        int n4 = (int)(n / 4);
        k_cvt<<<dim3((n4 + 255) / 256), 256, 0, stream>>>(s, d, n4);
    };
    cvt(e0_wih, e0wihB, (size_t)2 * 2048 * 512);
    cvt(e0_whh, e0whhB, (size_t)2 * 2048 * 512);
    cvt(e1_wih, e1wihB, (size_t)2 * 2048 * 1024);
    cvt(e1_whh, e1whhB, (size_t)2 * 2048 * 512);
    cvt(d_whh, dwhhB, (size_t)4096 * 1024);

    const size_t SLOT = (size_t)NB * 1024;  // ring slot elems
    hipMemsetAsync(h1, 0, SLOT * 2, stream);                            // slot 0
    hipMemsetAsync(h1 + (size_t)(LQ + 1) * SLOT, 0, SLOT * 2, stream);  // slot LQ+1
    hipMemsetAsync(encb, 0, SLOT * 2, stream);
    hipMemsetAsync(encb + (size_t)(LQ + 1) * SLOT, 0, SLOT * 2, stream);
    hipMemsetAsync(cstE, 0, (size_t)2 * 2 * NB * 512 * 4, stream);
    hipMemsetAsync(bars, 0, (size_t)1024 * BAR_STRIDE * 4, stream);
    hipMemsetAsync(prob + (size_t)NB * LQ * TT, 0, 4, stream);  // loss scalar

    // barrier-set regions: enc0 chunk cc -> sets [cc*CH ..], enc1 -> LQ + cc*CH,
    // decoder -> 2*LQ .. (needs 1 + 2*LQ = 321 sets; 1024 allocated)
    // ---- encoder layer 0 ----
    for (int cc = 0; cc < LQ / CH; ++cc) {
        int s0 = cc * CH;
        k_xg0c<<<dim3(CH * 2, 32, 2), 64, 0, stream>>>(ids, embed, e0wihB, xgc, s0);
        k_enc_chunk<<<dim3(128), 64, 0, stream>>>(h1, e0whhB, e0_b, xgc, cstE,
                                                  bars + (size_t)(cc * CH) * BAR_STRIDE,
                                                  s0, CH);
    }
    // ---- encoder layer 1 ----
    for (int cc = 0; cc < LQ / CH; ++cc) {
        int s0 = cc * CH;
        k_xg1c<<<dim3(CH * 2, 32, 2), 64, 0, stream>>>(h1, e1wihB, xgc, s0);
        k_enc_chunk<<<dim3(128), 64, 0, stream>>>(encb, e1whhB, e1_b, xgc,
                                                  cstE + (size_t)2 * NB * 512,
                                                  bars + (size_t)(LQ + cc * CH) * BAR_STRIDE,
                                                  s0, CH);
    }
    // ---- decoder (one persistent launch) ----
    k_dec_persist<<<dim3(128), 64, 0, stream>>>(encb, dwhhB, d_b, d_wih, out_w, out_b,
                                                tags, hseqD, hdec, idx,
                                                bars + (size_t)(2 * LQ) * BAR_STRIDE,
                                                prob, prob + (size_t)NB * LQ * TT);
}